// Round 8
// baseline (264.093 us; speedup 1.0000x reference)
//
#include <hip/hip_runtime.h>
#include <stdint.h>

// ksparse: per row of 4096x8192 f32, threshold = 513th largest (k=512),
// out = x * (x > thresh). Exact radix-select on the order-preserving uint32
// mapping: ONE 11-bit/2048-bin histogram pass, candidate compaction
// (~440 survivors on N(0,1) data), three 7-bit tail passes in wave 0.
//
// v8 = v7's LDS-DMA prefetch with its two measured confounds removed:
//  - v7 LDS was 50KB -> 3 blocks/CU but grid needed 4/CU -> 256 blocks ran
//    SOLO (occupancy 23.6%, +25us tail). v8 packs select state into ONE
//    histogram block: stage 32KB + hist 8KB = 40960B exactly -> 4 blocks/CU,
//    grid 1024 = exactly 4/CU, zero tail, 16 waves/CU.
//  - one histogram replica (hswz spreads banks; conflict cost measured
//    ~0.5us/dispatch, doubling it is cheap).
//  - overlay into dead hist after the pass-0 scan (B3): cand=hist[0..1279],
//    th=hist[1280..1663] (wave0 re-zeroes post-B4, in-wave ordered),
//    scalars=hist[1665..1667] (s_cnt zeroed by wave0 lane0 post-scan).
// Pipeline (verified clean in v7): per-wave quarter DMA ownership via
// __builtin_amdgcn_global_load_lds (zero VGPR cost), raw bar_lds barriers
// (no vmcnt drain), counted vmcnt(8) at loop bottom (drains prev stores +
// next row's DMA, keeps this row's stores in flight).

constexpr int COLS  = 8192;
constexpr int TPB   = 256;
constexpr int VPT   = 8;            // float4 per thread per row
constexpr int NBIN0 = 2048;         // pass-0 bins (11 bits)
constexpr int CAP   = 1280;         // candidate cap (expected ~440 on N(0,1))

// LDS word-offsets inside hist[] for the post-scan overlay:
constexpr int OFF_CAND = 0;         // [0..1279]   candidates
constexpr int OFF_TH   = 1280;      // [1280..1663] 3x128 tail histograms
constexpr int OFF_PK   = 1665;      // s_packed
constexpr int OFF_CNT  = 1666;      // s_cnt
constexpr int OFF_T    = 1667;      // s_T

__device__ __forceinline__ uint32_t map_f32(uint32_t u) {
  return (u & 0x80000000u) ? ~u : (u | 0x80000000u);
}
__device__ __forceinline__ float unmap_f32(uint32_t m) {
  return __uint_as_float((m & 0x80000000u) ? (m ^ 0x80000000u) : ~m);
}
// Top-11 bits of map_f32(u): positive: (u>>21)|0x400 ; negative: 0x7FF^(u>>21).
__device__ __forceinline__ uint32_t bin11(uint32_t u) {
  const uint32_t s = u >> 21;
  return (u & 0x80000000u) ? (0x7FFu ^ s) : (s | 0x400u);
}
// Word-index swizzle: XOR quad bits (2..4) with lane bits (5..7). Bijective,
// 16B-granular; makes wave0's 32-bins/lane scan reads conflict-free.
__device__ __forceinline__ uint32_t hswz(uint32_t w) {
  return w ^ ((w >> 3) & 0x1Cu);
}

// Workgroup barrier WITHOUT __syncthreads' vmcnt(0) drain. Memory clobbers
// on BOTH sides (barrier intrinsic is not a compiler fence) -- v6b/v7
// correctness-verified.
__device__ __forceinline__ void bar_lds() {
  asm volatile("s_waitcnt lgkmcnt(0)" ::: "memory");
  __builtin_amdgcn_s_barrier();
  asm volatile("" ::: "memory");
}

// Async 16B-wide global->LDS DMA (LDS dest = wave-uniform base + lane*16).
__device__ __forceinline__ void gl2lds16(const float* g, float* l) {
  __builtin_amdgcn_global_load_lds(
      (const __attribute__((address_space(1))) void*)g,
      (__attribute__((address_space(3))) void*)l, 16, 0, 0);
}

// Wave w stages its 8KB quarter of a 32KB row: 8 instructions x 1KB.
__device__ __forceinline__ void stage_row(const float* __restrict__ rowp,
                                          float* stage, int wave, int lane) {
  const float* g = rowp + (wave << 11) + (lane << 2);
  float* l = stage + (wave << 11);
#pragma unroll
  for (int i = 0; i < VPT; ++i)
    gl2lds16(g + i * 256, l + i * 256);
}

template <int RPB>
__global__ __launch_bounds__(TPB)
void ksparse_kernel(const float* __restrict__ in, const int* __restrict__ kptr,
                    float* __restrict__ out) {
  __shared__ __align__(16) uint32_t hist[NBIN0];   // 8KB: bins -> cand|th|scalars
  __shared__ __align__(16) float    stage[COLS];   // 32KB row staging (wave quarters)
  // total 40960B exactly -> 4 blocks/CU.

  const int t    = threadIdx.x;
  const int wave = t >> 6;
  const int lane = t & 63;
  const size_t row0 = (size_t)blockIdx.x * RPB;

  const uint32_t kbase = (uint32_t)(*kptr) + 1u; // rank from top: 513th largest

  // ---- prologue: DMA row 0 into the staging buffer ----
  stage_row(in + row0 * COLS, stage, wave, lane);

#pragma unroll
  for (int r = 0; r < RPB; ++r) {
    // ---- zero the histogram (dead since previous row's B5) ----
    uint4* h4 = (uint4*)hist;
    h4[t] = make_uint4(0u, 0u, 0u, 0u);
    h4[t + TPB] = make_uint4(0u, 0u, 0u, 0u);
    bar_lds(); // B1: zeroing visible

    if (r == 0) asm volatile("s_waitcnt vmcnt(0)" ::: "memory"); // row0 DMA only
    // (r>0: DMA(r) was drained by the previous iteration's bottom vmcnt(8))

    // ---- fused LDS->reg + histogram: wave reads its OWN quarter ----
    float4 v[VPT];
    const float4* sq = (const float4*)stage + (wave << 9) + lane;
#pragma unroll
    for (int i = 0; i < VPT; ++i) {
      v[i] = sq[i << 6]; // +1KB per step
      atomicAdd(&hist[hswz(bin11(__float_as_uint(v[i].x)))], 1u);
      atomicAdd(&hist[hswz(bin11(__float_as_uint(v[i].y)))], 1u);
      atomicAdd(&hist[hswz(bin11(__float_as_uint(v[i].z)))], 1u);
      atomicAdd(&hist[hswz(bin11(__float_as_uint(v[i].w)))], 1u);
    }
    // quarter consumed -> start next row's DMA into it; streams under select.
    if (r + 1 < RPB) {
      asm volatile("s_waitcnt lgkmcnt(0)" ::: "memory"); // my ds_reads done
      stage_row(in + (row0 + (size_t)(r + 1)) * COLS, stage, wave, lane);
    }
    bar_lds(); // B2: histogram visible

    // ---- pass-0 scan in wave 0: lane owns bins [32*lane, 32*lane+32) ----
    if (wave == 0) {
      const uint4* r0 = (const uint4*)&hist[0];
      uint32_t qs[8];
      uint32_t total = 0;
#pragma unroll
      for (int q = 0; q < 8; ++q) {
        const uint32_t Qs = (uint32_t)(8 * lane + q) ^ (uint32_t)(lane & 7);
        const uint4 a = r0[Qs];
        qs[q] = (a.x + a.y) + (a.z + a.w);
        total += qs[q];
      }
      uint32_t s = total; // inclusive suffix over lanes
#pragma unroll
      for (int off = 1; off < 64; off <<= 1) {
        const uint32_t tmp = __shfl_down(s, off, 64);
        s += (lane + off < 64) ? tmp : 0u;
      }
      const unsigned long long mb = __ballot(s >= kbase);
      const int lstar = 63 - __builtin_clzll(mb);
      if (lane == lstar) {
        uint32_t run = s - total;
        int qq = -1; uint32_t qab = 0;
#pragma unroll
        for (int q = 7; q >= 0; --q) {
          const uint32_t nrun = run + qs[q];
          if (qq < 0 && nrun >= kbase) { qq = q; qab = run; }
          run = nrun;
        }
        const uint32_t Qs = (uint32_t)(8 * lane + qq) ^ (uint32_t)(lane & 7);
        const uint4 a = r0[Qs];
        const uint32_t s3 = qab + a.w;
        const uint32_t s2 = s3 + a.z, s1 = s2 + a.y;
        uint32_t e, above;
        if (s3 >= kbase)      { e = 3u; above = qab; }
        else if (s2 >= kbase) { e = 2u; above = s3; }
        else if (s1 >= kbase) { e = 1u; above = s2; }
        else                  { e = 0u; above = s1; }
        const uint32_t d0 = (uint32_t)(lane * 32 + qq * 4) + e;
        hist[OFF_PK] = (d0 << 14) | above; // bins dead from here on
      }
      if (lane == 0) hist[OFF_CNT] = 0u;   // after all lanes' q-loop reads
    }
    bar_lds(); // B3: d0 + zeroed s_cnt published; bins now reusable

    const uint32_t pk = hist[OFF_PK];
    const uint32_t d0 = pk >> 14;

    // ---- compact candidates (bin == d0) into dead bin space ----
    uint32_t* cand = &hist[OFF_CAND];
#pragma unroll
    for (int i = 0; i < VPT; ++i) {
      uint32_t u;
      u = __float_as_uint(v[i].x);
      if (bin11(u) == d0) { const uint32_t x = atomicAdd(&hist[OFF_CNT], 1u); if (x < CAP) cand[x] = map_f32(u) & 0x1FFFFFu; }
      u = __float_as_uint(v[i].y);
      if (bin11(u) == d0) { const uint32_t x = atomicAdd(&hist[OFF_CNT], 1u); if (x < CAP) cand[x] = map_f32(u) & 0x1FFFFFu; }
      u = __float_as_uint(v[i].z);
      if (bin11(u) == d0) { const uint32_t x = atomicAdd(&hist[OFF_CNT], 1u); if (x < CAP) cand[x] = map_f32(u) & 0x1FFFFFu; }
      u = __float_as_uint(v[i].w);
      if (bin11(u) == d0) { const uint32_t x = atomicAdd(&hist[OFF_CNT], 1u); if (x < CAP) cand[x] = map_f32(u) & 0x1FFFFFu; }
    }
    bar_lds(); // B4: compaction done

    // ---- three 7-bit tail passes, entirely in wave 0 ----
    if (wave == 0) {
      // re-zero the th overlay (pass-0 incremented these words as bins)
      uint32_t* thb = &hist[OFF_TH];
#pragma unroll
      for (int i = 0; i < 6; ++i) thb[lane + i * 64] = 0u;
      asm volatile("s_waitcnt lgkmcnt(0)" ::: "memory"); // in-wave order

      const uint32_t cnt = hist[OFF_CNT];
      const uint32_t Cc = (cnt < (uint32_t)CAP) ? cnt : (uint32_t)CAP;
      uint32_t kk = kbase - (pk & 0x3FFFu);
      uint32_t tpref = 0;
#pragma unroll 1
      for (int j = 0; j < 3; ++j) {
        const int dsh = 14 - 7 * j;
        uint32_t* thj = &hist[OFF_TH + j * 128];
        for (uint32_t idx = (uint32_t)lane; idx < Cc; idx += 64u) {
          const uint32_t c = cand[idx];
          const bool ok = (j == 0) || ((c >> (dsh + 7)) == tpref);
          if (ok) atomicAdd(&thj[(c >> dsh) & 127u], 1u);
        }
        const uint32_t a = thj[lane], b = thj[64 + lane];
        uint32_t sb = b, sa = a;
#pragma unroll
        for (int off = 1; off < 64; off <<= 1) {
          const uint32_t t1 = __shfl_down(sb, off, 64);
          const uint32_t t2 = __shfl_down(sa, off, 64);
          const bool inr = (lane + off < 64);
          sb += inr ? t1 : 0u;
          sa += inr ? t2 : 0u;
        }
        const uint32_t tb = __shfl(sb, 0, 64); // total of bins 64..127
        sa += tb;
        const unsigned long long mbj = __ballot(sb >= kk);
        uint32_t d, ab;
        if (mbj) {
          const int hb = 63 - __builtin_clzll(mbj);
          const uint32_t nx = __shfl(sb, (hb + 1) & 63, 64);
          d = 64u + (uint32_t)hb;
          ab = (hb == 63) ? 0u : nx;
        } else {
          const unsigned long long ma = __ballot(sa >= kk); // nonzero by invariant
          const int ha = 63 - __builtin_clzll(ma);
          const uint32_t nx = __shfl(sa, (ha + 1) & 63, 64);
          d = (uint32_t)ha;
          ab = (ha == 63) ? tb : nx;
        }
        tpref = (tpref << 7) | d;
        kk -= ab;
      }
      if (lane == 0) hist[OFF_T] = (d0 << 21) | tpref;
    }
    bar_lds(); // B5: threshold published

    // ---- masked write with FLOAT compare (== reference's strict >) ----
    const float thr = unmap_f32(hist[OFF_T]);
    float4* op = (float4*)(out + (row0 + (size_t)r) * COLS) + (wave << 9) + lane;
#pragma unroll
    for (int i = 0; i < VPT; ++i) {
      float4 w;
      w.x = (v[i].x > thr) ? v[i].x : 0.0f;
      w.y = (v[i].y > thr) ? v[i].y : 0.0f;
      w.z = (v[i].z > thr) ? v[i].z : 0.0f;
      w.w = (v[i].w > thr) ? v[i].w : 0.0f;
      op[i << 6] = w;
    }
    // Counted drain (never vmcnt(0) in the loop): outstanding here =
    // [ST(r-1) x8, DMA(r+1) x8, ST(r) x8]; wait to <=8 drains prev stores +
    // next row's DMA (needed by next iteration's ds_reads), keeps this row's
    // 8 stores in flight under the next row's zero+hist phases.
    asm volatile("s_waitcnt vmcnt(8)" ::: "memory");
  }
}

extern "C" void kernel_launch(void* const* d_in, const int* in_sizes, int n_in,
                              void* d_out, int out_size, void* d_ws, size_t ws_size,
                              hipStream_t stream) {
  const float* in  = (const float*)d_in[0];
  const int*   k   = (const int*)d_in[1];
  float*       out = (float*)d_out;
  int rows = in_sizes[0] / COLS;
  if (rows < 1) rows = 1;
  if ((rows & 3) == 0) {
    ksparse_kernel<4><<<rows / 4, TPB, 0, stream>>>(in, k, out);
  } else {
    ksparse_kernel<1><<<rows, TPB, 0, stream>>>(in, k, out);
  }
}

// Round 9
// 235.222 us; speedup vs baseline: 1.1227x; 1.1227x over previous
//
#include <hip/hip_runtime.h>
#include <stdint.h>

// ksparse: per row of 4096x8192 f32, threshold = 513th largest (k=512),
// out = x * (x > thresh).
//
// v9: pivot-filter fast path. All pipelining variants (v2,v3,v6b,v7,v8)
// lost to the simple per-row structure (v1/v5 = 84us), and every version
// runs at hbm_bytes/dur ~= 2.4 TB/s -- structure-invariant. v9 attacks the
// remaining non-memory work: instead of a 2048-bin histogram over all 8192
// elements (8KB zero + 8192 LDS atomics + big scan + 3 tail passes), count
// elements > pivot (1.40f, expected 662+-25 for N(0,1) rows). If
// k+1 <= count <= 1024 (>=6 sigma), the rank-(k+1) element is among the
// candidates: compact their 32-bit mapped keys to LDS and wave0 radix-
// selects over ~662 elems with four 8-bit/256-bin passes, fully intra-wave
// (shfl broadcast, no LDS publishes). 3 block barriers/row (was 5/11).
// EXACT for arbitrary data: full-block 4x8-bit radix fallback if the count
// test fails (never taken on this input; prob ~1e-9/row).
// LDS 18.4KB -> ~5.3KB => 8 blocks/CU co-resident (was 3.3) for TLP.
// Loads issued first; raw bar_lds barriers (no vmcnt drain; v6b-verified).

constexpr int COLS = 8192;
constexpr int TPB  = 256;
constexpr int VPT  = 8;       // float4 per thread
constexpr int CAP  = 1024;    // candidate capacity (expected ~662)

__device__ __forceinline__ uint32_t map_f32(uint32_t u) {
  return (u & 0x80000000u) ? ~u : (u | 0x80000000u);
}
__device__ __forceinline__ float unmap_f32(uint32_t m) {
  return __uint_as_float((m & 0x80000000u) ? (m ^ 0x80000000u) : ~m);
}

// Workgroup barrier WITHOUT __syncthreads' vmcnt(0) drain. lgkmcnt(0) makes
// LDS ops visible; memory clobbers on BOTH sides (the barrier intrinsic is
// not a compiler fence). Correctness-verified in v6b/v7/v8.
__device__ __forceinline__ void bar_lds() {
  asm volatile("s_waitcnt lgkmcnt(0)" ::: "memory");
  __builtin_amdgcn_s_barrier();
  asm volatile("" ::: "memory");
}

__global__ void ksparse_kernel(const float* __restrict__ in,
                               const int* __restrict__ kptr,
                               float* __restrict__ out) {
  __shared__ __align__(16) uint32_t cand[CAP]; // 4KB candidate keys (mapped)
  __shared__ __align__(16) uint32_t bins[256]; // 1KB radix bins
  __shared__ uint32_t s_wtot[4];               // per-wave pivot counts
  __shared__ uint32_t s_cidx;                  // compaction cursor
  __shared__ uint32_t s_T;                     // selected mapped threshold
  __shared__ uint32_t s_sel;                   // fallback digit publish

  const int t    = threadIdx.x;
  const int wave = t >> 6;
  const int lane = t & 63;
  const size_t rowbase = (size_t)blockIdx.x * COLS;

  const float PIV = 1.40f; // fast-path pivot (N(0,1): P(x>1.40)*8192 ~ 662)

  // ---- issue all loads first; everything below overlaps their latency ----
  const float4* inp = (const float4*)(in + rowbase);
  float4 v[VPT];
#pragma unroll
  for (int i = 0; i < VPT; ++i) v[i] = inp[t + i * TPB];

  if (t == 0) s_cidx = 0u;
  const uint32_t kbase = (uint32_t)(*kptr) + 1u; // rank from top: 513th largest

  // ---- count elements > pivot (one compare per element) ----
  uint32_t c = 0;
#pragma unroll
  for (int i = 0; i < VPT; ++i) {
    c += (v[i].x > PIV) ? 1u : 0u;
    c += (v[i].y > PIV) ? 1u : 0u;
    c += (v[i].z > PIV) ? 1u : 0u;
    c += (v[i].w > PIV) ? 1u : 0u;
  }
#pragma unroll
  for (int off = 1; off < 64; off <<= 1) {
    const uint32_t tmp = __shfl_down(c, off, 64);
    c += (lane + off < 64) ? tmp : 0u;
  }
  if (lane == 0) s_wtot[wave] = c; // distinct addresses: no race, no atomic
  bar_lds(); // B1: counts + zeroed cursor visible

  const uint32_t cnt = s_wtot[0] + s_wtot[1] + s_wtot[2] + s_wtot[3];

  uint32_t T;
  if (cnt >= kbase && cnt <= (uint32_t)CAP) {
    // ================= FAST PATH =================
    // compact mapped keys of all candidates (~662) into LDS
#pragma unroll
    for (int i = 0; i < VPT; ++i) {
      if (v[i].x > PIV) { const uint32_t x = atomicAdd(&s_cidx, 1u); cand[x] = map_f32(__float_as_uint(v[i].x)); }
      if (v[i].y > PIV) { const uint32_t x = atomicAdd(&s_cidx, 1u); cand[x] = map_f32(__float_as_uint(v[i].y)); }
      if (v[i].z > PIV) { const uint32_t x = atomicAdd(&s_cidx, 1u); cand[x] = map_f32(__float_as_uint(v[i].z)); }
      if (v[i].w > PIV) { const uint32_t x = atomicAdd(&s_cidx, 1u); cand[x] = map_f32(__float_as_uint(v[i].w)); }
    }
    bar_lds(); // B2: candidates visible

    // wave0: four 8-bit radix passes over cnt candidates, fully intra-wave
    if (wave == 0) {
      uint32_t kk = kbase;
      uint32_t pref = 0;
#pragma unroll 1
      for (int j = 0; j < 4; ++j) {
        const int sh = 24 - 8 * j;
        ((uint4*)bins)[lane] = make_uint4(0u, 0u, 0u, 0u); // 64x16B = 256 bins
        asm volatile("s_waitcnt lgkmcnt(0)" ::: "memory");  // in-wave order
        for (uint32_t idx = (uint32_t)lane; idx < cnt; idx += 64u) {
          const uint32_t cd = cand[idx];
          const bool ok = (j == 0) || ((cd >> (sh + 8)) == pref);
          if (ok) atomicAdd(&bins[(cd >> sh) & 255u], 1u);
        }
        asm volatile("s_waitcnt lgkmcnt(0)" ::: "memory");  // bins settled
        const uint4 bq = ((const uint4*)bins)[lane]; // lane owns bins 4l..4l+3
        const uint32_t s3 = bq.w, s2 = s3 + bq.z, s1 = s2 + bq.y;
        const uint32_t total = s1 + bq.x;
        uint32_t s = total; // inclusive suffix over lanes (desc value order)
#pragma unroll
        for (int off = 1; off < 64; off <<= 1) {
          const uint32_t tmp = __shfl_down(s, off, 64);
          s += (lane + off < 64) ? tmp : 0u;
        }
        const unsigned long long mb = __ballot(s >= kk); // lanes 0..l*
        const int lstar = 63 - __builtin_clzll(mb);
        const uint32_t above0 = s - total; // count in quads above mine
        uint32_t d_loc, ab_loc;
        if (above0 + s3 >= kk)      { d_loc = 3u; ab_loc = above0; }
        else if (above0 + s2 >= kk) { d_loc = 2u; ab_loc = above0 + s3; }
        else if (above0 + s1 >= kk) { d_loc = 1u; ab_loc = above0 + s2; }
        else                        { d_loc = 0u; ab_loc = above0 + s1; }
        const uint32_t dig = (uint32_t)lstar * 4u + __shfl(d_loc, lstar, 64);
        const uint32_t ab  = __shfl(ab_loc, lstar, 64);
        pref = (pref << 8) | dig;
        kk -= ab;
      }
      if (lane == 0) s_T = pref; // full 32-bit mapped threshold
    }
    bar_lds(); // B3: threshold published
    T = s_T;
  } else {
    // ================= EXACT FALLBACK (block-uniform branch) =================
    // full-block 4x8-bit radix over all 8192 elements (never taken on the
    // bench input; keeps the kernel exact for arbitrary data).
    uint32_t kk = kbase;
    uint32_t pref = 0;
#pragma unroll 1
    for (int j = 0; j < 4; ++j) {
      const int sh = 24 - 8 * j;
      if (t < 64) ((uint4*)bins)[t] = make_uint4(0u, 0u, 0u, 0u);
      bar_lds();
#pragma unroll
      for (int i = 0; i < VPT; ++i) {
        uint32_t m;
        m = map_f32(__float_as_uint(v[i].x));
        if (j == 0 || (m >> (sh + 8)) == pref) atomicAdd(&bins[(m >> sh) & 255u], 1u);
        m = map_f32(__float_as_uint(v[i].y));
        if (j == 0 || (m >> (sh + 8)) == pref) atomicAdd(&bins[(m >> sh) & 255u], 1u);
        m = map_f32(__float_as_uint(v[i].z));
        if (j == 0 || (m >> (sh + 8)) == pref) atomicAdd(&bins[(m >> sh) & 255u], 1u);
        m = map_f32(__float_as_uint(v[i].w));
        if (j == 0 || (m >> (sh + 8)) == pref) atomicAdd(&bins[(m >> sh) & 255u], 1u);
      }
      bar_lds();
      if (wave == 0) {
        const uint4 bq = ((const uint4*)bins)[lane];
        const uint32_t s3 = bq.w, s2 = s3 + bq.z, s1 = s2 + bq.y;
        const uint32_t total = s1 + bq.x;
        uint32_t s = total;
#pragma unroll
        for (int off = 1; off < 64; off <<= 1) {
          const uint32_t tmp = __shfl_down(s, off, 64);
          s += (lane + off < 64) ? tmp : 0u;
        }
        const unsigned long long mb = __ballot(s >= kk);
        const int lstar = 63 - __builtin_clzll(mb);
        const uint32_t above0 = s - total;
        uint32_t d_loc, ab_loc;
        if (above0 + s3 >= kk)      { d_loc = 3u; ab_loc = above0; }
        else if (above0 + s2 >= kk) { d_loc = 2u; ab_loc = above0 + s3; }
        else if (above0 + s1 >= kk) { d_loc = 1u; ab_loc = above0 + s2; }
        else                        { d_loc = 0u; ab_loc = above0 + s1; }
        const uint32_t dig = (uint32_t)lstar * 4u + __shfl(d_loc, lstar, 64);
        const uint32_t ab  = __shfl(ab_loc, lstar, 64);
        if (lane == 0) s_sel = (dig << 24) | ab; // ab < 8192 fits 24 bits
      }
      bar_lds();
      const uint32_t sel = s_sel;
      pref = (pref << 8) | (sel >> 24);
      kk -= (sel & 0xFFFFFFu);
    }
    T = pref;
  }

  // ---- masked write with FLOAT compare (== reference's strict >) ----
  const float thr = unmap_f32(T);
  float4* op = (float4*)(out + rowbase);
#pragma unroll
  for (int i = 0; i < VPT; ++i) {
    float4 w;
    w.x = (v[i].x > thr) ? v[i].x : 0.0f;
    w.y = (v[i].y > thr) ? v[i].y : 0.0f;
    w.z = (v[i].z > thr) ? v[i].z : 0.0f;
    w.w = (v[i].w > thr) ? v[i].w : 0.0f;
    op[t + i * TPB] = w;
  }
}

extern "C" void kernel_launch(void* const* d_in, const int* in_sizes, int n_in,
                              void* d_out, int out_size, void* d_ws, size_t ws_size,
                              hipStream_t stream) {
  const float* in  = (const float*)d_in[0];
  const int*   k   = (const int*)d_in[1];
  float*       out = (float*)d_out;
  int rows = in_sizes[0] / COLS;
  if (rows < 1) rows = 1;
  ksparse_kernel<<<rows, TPB, 0, stream>>>(in, k, out);
}